// Round 4
// baseline (233.314 us; speedup 1.0000x reference)
//
#include <hip/hip_runtime.h>
#include <hip/hip_bf16.h>
#include <stdint.h>

// MFMA fragment types (gfx950)
typedef __bf16 bf16x8 __attribute__((ext_vector_type(8)));
typedef float  f32x4  __attribute__((ext_vector_type(4)));
typedef short  short4v __attribute__((ext_vector_type(4)));

__device__ __forceinline__ unsigned short f2bf(float f) {
  union { float f; unsigned u; } x; x.f = f;
  unsigned r = x.u + 0x7fffu + ((x.u >> 16) & 1u);   // RNE
  return (unsigned short)(r >> 16);
}

// pack two f32 -> bf16x2 dword (RNE), low half = a
__device__ __forceinline__ unsigned pack_rne(float a, float b) {
  unsigned ua = __float_as_uint(a), ub = __float_as_uint(b);
  ua = ua + 0x7fffu + ((ua >> 16) & 1u);
  ub = ub + 0x7fffu + ((ub >> 16) & 1u);
  return __builtin_amdgcn_perm(ub, ua, 0x07060302);
}

// 16x16x16 bf16 MFMA: B-operand layout == 16x16 C/D layout (k=qd*4+j <-> row=qd*4+rg)
__device__ __forceinline__ f32x4 mfma16(short4v a, short4v b, f32x4 c) {
#if __has_builtin(__builtin_amdgcn_mfma_f32_16x16x16bf16_1k)
  return __builtin_amdgcn_mfma_f32_16x16x16bf16_1k(a, b, c, 0, 0, 0);
#else
  f32x4 d;
  asm volatile("v_mfma_f32_16x16x16_bf16 %0, %1, %2, %3\n\ts_nop 7\n\ts_nop 7"
               : "=v"(d) : "v"(a), "v"(b), "v"(c));
  return d;
#endif
}

// async global->LDS, 16B per lane; LDS dest = wave-uniform base + lane*16
__device__ __forceinline__ void gll16(const void* g, void* l) {
  __builtin_amdgcn_global_load_lds((const __attribute__((address_space(1))) void*)g,
                                   (__attribute__((address_space(3))) void*)l, 16, 0, 0);
}

// ---------------- fused prep: convert q/k/v, transpose weights, init out ----------------
__global__ __launch_bounds__(256) void k_prep(
    const float* __restrict__ q, const float* __restrict__ k, const float* __restrict__ v,
    const float* __restrict__ Wq, const float* __restrict__ Wk,
    const float* __restrict__ Wv, const float* __restrict__ Wo,
    const float* __restrict__ bo,
    unsigned short* __restrict__ qb, unsigned short* __restrict__ kb,
    unsigned short* __restrict__ vb,
    unsigned short* __restrict__ Wqt, unsigned short* __restrict__ Wkt,
    unsigned short* __restrict__ Wvt, unsigned short* __restrict__ Wot,
    float* __restrict__ out) {
  __shared__ float tt[32][33];
  int b = blockIdx.x, tid = threadIdx.x;
  if (b < 12288) {                       // fp32->bf16 convert q/k/v
    int z = b >> 12;
    const float* src = z == 0 ? q : z == 1 ? k : v;
    unsigned short* dst = z == 0 ? qb : z == 1 ? kb : vb;
    size_t i = (size_t)(b & 4095) * 256 + tid;
    float4 f = ((const float4*)src)[i];
    ushort4 o;
    o.x = f2bf(f.x); o.y = f2bf(f.y); o.z = f2bf(f.z); o.w = f2bf(f.w);
    ((ushort4*)dst)[i] = o;
  } else if (b < 15424) {                // transpose+convert weights -> Wt[C][1024]
    int t = b - 12288;
    const float* W; unsigned short* Wt; int C, c0, r0;
    if (t < 3072) {
      int z = t >> 10;
      W = z == 0 ? Wq : z == 1 ? Wk : Wv;
      Wt = z == 0 ? Wqt : z == 1 ? Wkt : Wvt;
      C = 1024; int tile = t & 1023;
      c0 = (tile & 31) * 32; r0 = (tile >> 5) * 32;
    } else {
      int t2 = t - 3072;
      W = Wo; Wt = Wot; C = 64;
      c0 = (t2 & 1) * 32; r0 = (t2 >> 1) * 32;
    }
    int tx = tid & 31, ty = tid >> 5;
    #pragma unroll
    for (int i = 0; i < 32; i += 8)
      tt[ty + i][tx] = W[(size_t)(r0 + ty + i) * C + c0 + tx];
    __syncthreads();
    #pragma unroll
    for (int i = 0; i < 32; i += 8)
      Wt[(size_t)(c0 + ty + i) * 1024 + r0 + tx] = f2bf(tt[tx][ty + i]);
  } else {                               // out = broadcast bias (oproj atomics add onto it)
    int t3 = b - 15424;
    int i = t3 * 1024 + tid * 4;
    float4 bv4 = *(const float4*)(bo + (i & 63));
    *(float4*)(out + i) = bv4;
  }
}

// ---------------- QKV projection GEMM: [4096x1024]@[1024x1024]+b, BK=64 ----------------
__global__ __launch_bounds__(256, 3) void k_proj(
    const unsigned short* __restrict__ qb, const unsigned short* __restrict__ kb,
    const unsigned short* __restrict__ vb,
    const unsigned short* __restrict__ Wqt, const unsigned short* __restrict__ Wkt,
    const unsigned short* __restrict__ Wvt,
    const float* __restrict__ bq, const float* __restrict__ bk, const float* __restrict__ bv,
    unsigned short* __restrict__ qh, unsigned short* __restrict__ kh,
    unsigned short* __restrict__ vht) {
  int z = blockIdx.z;
  const unsigned short* A  = z == 0 ? qb  : z == 1 ? kb  : vb;
  const unsigned short* Bt = z == 0 ? Wqt : z == 1 ? Wkt : Wvt;
  const float* bias = z == 0 ? bq : z == 1 ? bk : bv;

  int m0 = blockIdx.y * 128;
  int n0 = blockIdx.x * 128;

  __shared__ __attribute__((aligned(16))) unsigned short As[128 * 64];
  __shared__ __attribute__((aligned(16))) unsigned short Bs[128 * 64];

  int tid = threadIdx.x;
  int w = tid >> 6, lane = tid & 63;
  int wm = w >> 1, wn = w & 1;
  int lr = lane & 15, lk = lane >> 4;

  f32x4 acc[4][4] = {};

  for (int k0 = 0; k0 < 1024; k0 += 64) {
    #pragma unroll
    for (int i = 0; i < 4; ++i) {        // A tile 128x64
      int cc = i * 256 + tid;
      int r = cc >> 3;
      int j = (cc & 7) ^ (r & 7);
      gll16(A + (size_t)(m0 + r) * 1024 + k0 + j * 8, As + (size_t)(i * 256 + w * 64) * 8);
    }
    #pragma unroll
    for (int i = 0; i < 4; ++i) {        // B tile 128x64
      int cc = i * 256 + tid;
      int r = cc >> 3;
      int j = (cc & 7) ^ (r & 7);
      gll16(Bt + (size_t)(n0 + r) * 1024 + k0 + j * 8, Bs + (size_t)(i * 256 + w * 64) * 8);
    }
    __syncthreads();
    #pragma unroll
    for (int ks = 0; ks < 2; ++ks) {
      bf16x8 af[4], bfr[4];
      #pragma unroll
      for (int mt = 0; mt < 4; ++mt) {
        int r = wm * 64 + mt * 16 + lr;
        af[mt] = *(const bf16x8*)(As + r * 64 + ((ks * 4 + lk) ^ (r & 7)) * 8);
      }
      #pragma unroll
      for (int nt = 0; nt < 4; ++nt) {
        int r = wn * 64 + nt * 16 + lr;
        bfr[nt] = *(const bf16x8*)(Bs + r * 64 + ((ks * 4 + lk) ^ (r & 7)) * 8);
      }
      #pragma unroll
      for (int mt = 0; mt < 4; ++mt)
        #pragma unroll
        for (int nt = 0; nt < 4; ++nt)
          acc[mt][nt] = __builtin_amdgcn_mfma_f32_16x16x32_bf16(af[mt], bfr[nt], acc[mt][nt], 0, 0, 0);
    }
    __syncthreads();
  }

  // epilogue: bias (+scale for q), scatter to attention layouts
  #pragma unroll
  for (int nt = 0; nt < 4; ++nt) {
    int n = n0 + wn * 64 + nt * 16 + lr;
    float bv_ = bias[n];
    int h = n >> 6, d = n & 63;
    #pragma unroll
    for (int mt = 0; mt < 4; ++mt) {
      int mbase = m0 + wm * 64 + mt * 16 + lk * 4;
      int b = mbase >> 11, s = mbase & 2047;
      if (z == 2) {
        size_t o = ((size_t)(b * 16 + h) * 64 + d) * 2048 + s;   // 4 consecutive s
        ushort4 pk;
        pk.x = f2bf(acc[mt][nt][0] + bv_);
        pk.y = f2bf(acc[mt][nt][1] + bv_);
        pk.z = f2bf(acc[mt][nt][2] + bv_);
        pk.w = f2bf(acc[mt][nt][3] + bv_);
        *(ushort4*)(vht + o) = pk;
      } else {
        unsigned short* dst = (z == 0) ? qh : kh;
        float sc = (z == 0) ? 0.125f : 1.0f;   // scale = ATT_DIM^-0.5, exact pow2
        #pragma unroll
        for (int rg = 0; rg < 4; ++rg) {
          float val = (acc[mt][nt][rg] + bv_) * sc;
          float pv = __shfl_xor(val, 1, 64);
          if ((lr & 1) == 0) {   // even-d lane packs (d, d+1) -> 4B store
            unsigned pkv = pack_rne(val, pv);
            *(unsigned*)(dst + ((size_t)(b * 16 + h) * 2048 + (s + rg)) * 64 + d) = pkv;
          }
        }
      }
    }
  }
}

// ---------------- fused attention, S^T formulation ----------------
// S^T = K @ Q^T (MFMA 16x16x32) -> P^T in C-layout (rows=keys). C-layout IS the
// B-operand layout of 16x16x16 MFMA, so PV consumes pk registers directly.
// Weight: softmax ratio only needs w ∝ exp(sigmoid(s)); sigmoid(s)-0.5 = 0.5*tanh(s/2),
// approximated by a degree-7 odd interpolating poly (nodes 1,2,3,4 in s; |s| clamped
// to 4; tanh abs err <=1.4e-3 for |s|<=2 -> weight rel err ~7e-4 < bf16 lsb 4e-3).
// Per-row constant offsets in the exponent cancel in the O/denominator ratio.
// Denominator = ones-row MFMA over the SAME truncated bf16 P the numerator uses.
__global__ __launch_bounds__(256, 4) void k_attn(
    const unsigned short* __restrict__ qh, const unsigned short* __restrict__ kh,
    const unsigned short* __restrict__ vht, unsigned short* __restrict__ attout) {
  int bh = blockIdx.y;
  int q0 = blockIdx.x * 64;
  const unsigned short* Q = qh + (size_t)bh * 2048 * 64;
  const unsigned short* Kg = kh + (size_t)bh * 2048 * 64;
  const unsigned short* Vg = vht + (size_t)bh * 64 * 2048;   // [64 d][2048 s]

  __shared__ __attribute__((aligned(16))) unsigned short KV[16384];  // 2x(K 4096 + V 4096)
  __shared__ float lsum[64];

  int tid = threadIdx.x;
  int w = tid >> 6, lane = tid & 63;
  int wm = w >> 1, wn = w & 1;          // wm: key-half of tile, wn: q-half
  int c = lane & 15, qd = lane >> 4;

  // Q fragments straight from global (one-time, 16B/lane): B[k=d][n=q]
  bf16x8 qf[2][2];
  #pragma unroll
  for (int nt = 0; nt < 2; ++nt)
    #pragma unroll
    for (int ks = 0; ks < 2; ++ks)
      qf[nt][ks] = *(const bf16x8*)(Q + (size_t)(q0 + wn * 32 + nt * 16 + c) * 64 + ks * 32 + qd * 8);

  // loop-invariant staging offsets (K rows stride 64; V rows stride 2048)
  size_t kOff[2], vOff[2]; int lOff[2];
  #pragma unroll
  for (int i = 0; i < 2; ++i) {
    int cc = i * 256 + w * 64 + lane;
    int r = cc >> 3;
    int j = (cc & 7) ^ (r & 7);
    kOff[i] = (size_t)r * 64 + j * 8;
    vOff[i] = (size_t)r * 2048 + j * 8;
    lOff[i] = (i * 256 + w * 64) * 8;
  }

  // stage tile 0 into buffer 0
  #pragma unroll
  for (int i = 0; i < 2; ++i) {
    gll16(Kg + kOff[i], KV + lOff[i]);
    gll16(Vg + vOff[i], KV + 4096 + lOff[i]);
  }
  Kg += 4096; Vg += 64;

  // loop-invariant frag addresses
  int kfA[2][2], vfA[4][2];
  #pragma unroll
  for (int mt = 0; mt < 2; ++mt) {
    int r = wm * 32 + mt * 16 + c;
    #pragma unroll
    for (int ks = 0; ks < 2; ++ks)
      kfA[mt][ks] = r * 64 + ((ks * 4 + qd) ^ (r & 7)) * 8;
  }
  #pragma unroll
  for (int dt = 0; dt < 4; ++dt) {
    int r = dt * 16 + c;
    #pragma unroll
    for (int mt = 0; mt < 2; ++mt)
      vfA[dt][mt] = r * 64 + ((4 * wm + 2 * mt + (qd >> 1)) ^ (r & 7)) * 8 + (qd & 1) * 4;
  }

  // ones A-fragment for denominator MFMA (bf16 1.0 = 0x3F80)
  const short one_bf = (short)0x3F80;
  short4v ones = {one_bf, one_bf, one_bf, one_bf};

  __syncthreads();

  f32x4 o[4][2] = {};                   // O^T partial [64 d][32 q] over this wave's keys
  f32x4 qacc[2] = {};                   // denominator: ones-row MFMA (all rows identical)

  for (int kt = 0; kt < 32; ++kt) {
    unsigned short* Kc = KV + (kt & 1) * 8192;
    unsigned short* Vc = Kc + 4096;
    if (kt + 1 < 32) {                  // prefetch next tile into other buffer
      unsigned short* Kn = KV + ((kt & 1) ^ 1) * 8192;
      #pragma unroll
      for (int i = 0; i < 2; ++i) {
        gll16(Kg + kOff[i], Kn + lOff[i]);
        gll16(Vg + vOff[i], Kn + 4096 + lOff[i]);
      }
      Kg += 4096; Vg += 64;
    }

    // S^T: D[key][q], wave tile 32 keys x 32 q
    f32x4 s[2][2] = {};
    #pragma unroll
    for (int ks = 0; ks < 2; ++ks) {
      bf16x8 kf[2];
      #pragma unroll
      for (int mt = 0; mt < 2; ++mt)
        kf[mt] = *(const bf16x8*)(Kc + kfA[mt][ks]);
      #pragma unroll
      for (int mt = 0; mt < 2; ++mt)
        #pragma unroll
        for (int nt = 0; nt < 2; ++nt)
          s[mt][nt] = __builtin_amdgcn_mfma_f32_16x16x32_bf16(kf[mt], qf[nt][ks], s[mt][nt], 0, 0, 0);
    }

    // w = exp(0.5*tanh(s/2)) via odd poly + single exp; truncate to bf16, pack
    unsigned pk[2][2][2];
    #pragma unroll
    for (int mt = 0; mt < 2; ++mt)
      #pragma unroll
      for (int nt = 0; nt < 2; ++nt) {
        unsigned wu[4];
        #pragma unroll
        for (int rg = 0; rg < 4; ++rg) {
          float sv = __builtin_amdgcn_fmed3f(s[mt][nt][rg], -4.0f, 4.0f);
          float z = sv * sv;
          float p = fmaf(z, fmaf(z, fmaf(z, -2.7201e-5f, 1.0864656e-3f),
                                  -1.8414438e-2f), 2.4841365e-1f) * sv;
          float e = __expf(p);
          wu[rg] = __float_as_uint(e) & 0xffff0000u;
        }
        pk[mt][nt][0] = __builtin_amdgcn_perm(wu[1], wu[0], 0x07060302);
        pk[mt][nt][1] = __builtin_amdgcn_perm(wu[3], wu[2], 0x07060302);
      }

    // PV: O^T[d][q] += V^T[d][k] P^T[k][q]; pk dwords ARE the 16x16x16 B-frags.
    // Denominator rides the MFMA pipe: qacc += 1^T @ P^T (same truncated values).
    short4v vfr[4][2];
    #pragma unroll
    for (int dt = 0; dt < 4; ++dt)
      #pragma unroll
      for (int mt = 0; mt < 2; ++mt)
        vfr[dt][mt] = *(const short4v*)(Vc + vfA[dt][mt]);
    #pragma unroll
    for (int nt = 0; nt < 2; ++nt)
      #pragma unroll
      for (int mt = 0; mt < 2; ++mt) {
        union { unsigned u[2]; short4v s4; } bb;
        bb.u[0] = pk[mt][nt][0];
        bb.u[1] = pk[mt][nt][1];
        qacc[nt] = mfma16(ones, bb.s4, qacc[nt]);
        #pragma unroll
        for (int dt = 0; dt < 4; ++dt)
          o[dt][nt] = mfma16(vfr[dt][mt], bb.s4, o[dt][nt]);
      }
    __syncthreads();
  }

  // cross-wave (wm) reduction through LDS (KV dead after last barrier)
  float* Ored = (float*)KV;             // [64 q][64 d] f32 = 16KB
  if (wm == 1) {
    #pragma unroll
    for (int nt = 0; nt < 2; ++nt) {
      int ql = wn * 32 + nt * 16 + c;
      #pragma unroll
      for (int dt = 0; dt < 4; ++dt)
        *(f32x4*)(Ored + ql * 64 + dt * 16 + qd * 4) = o[dt][nt];
      if (qd == 0) lsum[ql] = qacc[nt][0];
    }
  }
  __syncthreads();
  if (wm == 0) {
    int b = bh >> 4, h = bh & 15;
    #pragma unroll
    for (int nt = 0; nt < 2; ++nt) {
      int ql = wn * 32 + nt * 16 + c;
      float inv = __builtin_amdgcn_rcpf(qacc[nt][0] + lsum[ql]);
      size_t rowoff = ((size_t)(b * 2048 + q0 + ql)) * 1024 + h * 64;
      #pragma unroll
      for (int dt = 0; dt < 4; ++dt) {
        f32x4 r = *(const f32x4*)(Ored + ql * 64 + dt * 16 + qd * 4);
        f32x4 t = o[dt][nt];
        uint2 pko;
        pko.x = pack_rne((t[0] + r[0]) * inv, (t[1] + r[1]) * inv);
        pko.y = pack_rne((t[2] + r[2]) * inv, (t[3] + r[3]) * inv);
        *(uint2*)(attout + rowoff + dt * 16 + qd * 4) = pko;
      }
    }
  }
}

// ---------------- output projection: k-split x4, atomics onto bias-init out ----------------
__global__ __launch_bounds__(256) void k_oproj(
    const unsigned short* __restrict__ attout, const unsigned short* __restrict__ Wot,
    float* __restrict__ out) {
  int m0 = blockIdx.x * 64;
  int kbase = blockIdx.y * 256;
  __shared__ __attribute__((aligned(16))) unsigned short As[64 * 32];
  __shared__ __attribute__((aligned(16))) unsigned short Bs[64 * 32];
  int tid = threadIdx.x;
  int w = tid >> 6, lane = tid & 63;
  int lr = lane & 15, lk = lane >> 4;

  f32x4 acc[4] = {};

  for (int k0 = kbase; k0 < kbase + 256; k0 += 32) {
    {
      int cc = tid;
      int r = cc >> 2;
      int j = (cc & 3) ^ ((r >> 1) & 3);
      gll16(attout + (size_t)(m0 + r) * 1024 + k0 + j * 8, As + (size_t)(w * 64) * 8);
      gll16(Wot + (size_t)r * 1024 + k0 + j * 8, Bs + (size_t)(w * 64) * 8);
    }
    __syncthreads();
    bf16x8 af, bfr[4];
    {
      int r = w * 16 + lr;
      af = *(const bf16x8*)(As + r * 32 + ((lk ^ ((r >> 1) & 3))) * 8);
    }
    #pragma unroll
    for (int nt = 0; nt < 4; ++nt) {
      int r = nt * 16 + lr;
      bfr[nt] = *(const bf16x8*)(Bs + r * 32 + ((lk ^ ((r >> 1) & 3))) * 8);
    }
    #pragma unroll
    for (int nt = 0; nt < 4; ++nt)
      acc[nt] = __builtin_amdgcn_mfma_f32_16x16x32_bf16(af, bfr[nt], acc[nt], 0, 0, 0);
    __syncthreads();
  }
  #pragma unroll
  for (int nt = 0; nt < 4; ++nt) {
    int n = nt * 16 + lr;
    #pragma unroll
    for (int rg = 0; rg < 4; ++rg) {
      int m = m0 + w * 16 + lk * 4 + rg;
      atomicAdd(&out[(size_t)m * 64 + n], acc[nt][rg]);
    }
  }
}

extern "C" void kernel_launch(void* const* d_in, const int* in_sizes, int n_in,
                              void* d_out, int out_size, void* d_ws, size_t ws_size,
                              hipStream_t stream) {
  const float* q  = (const float*)d_in[0];
  const float* k  = (const float*)d_in[1];
  const float* v  = (const float*)d_in[2];
  const float* Wq = (const float*)d_in[3];
  const float* bq = (const float*)d_in[4];
  const float* Wk = (const float*)d_in[5];
  const float* bk = (const float*)d_in[6];
  const float* Wv = (const float*)d_in[7];
  const float* bv = (const float*)d_in[8];
  const float* Wo = (const float*)d_in[9];
  const float* bo = (const float*)d_in[10];
  float* out = (float*)d_out;

  char* ws = (char*)d_ws;
  const size_t MB = 1024 * 1024;
  unsigned short* qb  = (unsigned short*)(ws + 0 * MB);   // q bf16 [4096][1024]
  unsigned short* kb  = (unsigned short*)(ws + 8 * MB);
  unsigned short* vb  = (unsigned short*)(ws + 16 * MB);
  unsigned short* Wqt = (unsigned short*)(ws + 24 * MB);  // W^T bf16 [1024][1024]
  unsigned short* Wkt = (unsigned short*)(ws + 26 * MB);
  unsigned short* Wvt = (unsigned short*)(ws + 28 * MB);
  unsigned short* Wot = (unsigned short*)(ws + 30 * MB);  // Wo^T bf16 [64][1024]
  unsigned short* qh  = (unsigned short*)(ws + 32 * MB);  // [B,H,S,64] scaled
  unsigned short* kh  = (unsigned short*)(ws + 40 * MB);  // [B,H,S,64]
  unsigned short* vht = (unsigned short*)(ws + 48 * MB);  // [B,H,64,S]
  unsigned short* att = (unsigned short*)(ws + 56 * MB);  // [4096][1024]

  k_prep<<<dim3(15680), dim3(256), 0, stream>>>(q, k, v, Wq, Wk, Wv, Wo, bo,
                                                qb, kb, vb, Wqt, Wkt, Wvt, Wot, out);
  k_proj<<<dim3(8, 32, 3), dim3(256), 0, stream>>>(qb, kb, vb, Wqt, Wkt, Wvt,
                                                   bq, bk, bv, qh, kh, vht);
  k_attn<<<dim3(32, 32), dim3(256), 0, stream>>>(qh, kh, vht, att);
  k_oproj<<<dim3(64, 4), dim3(256), 0, stream>>>(att, Wot, out);
}

// Round 5
// 219.448 us; speedup vs baseline: 1.0632x; 1.0632x over previous
//
#include <hip/hip_runtime.h>
#include <hip/hip_bf16.h>
#include <stdint.h>

// MFMA fragment types (gfx950)
typedef __bf16 bf16x8 __attribute__((ext_vector_type(8)));
typedef float  f32x4  __attribute__((ext_vector_type(4)));
typedef short  short4v __attribute__((ext_vector_type(4)));

__device__ __forceinline__ unsigned short f2bf(float f) {
  union { float f; unsigned u; } x; x.f = f;
  unsigned r = x.u + 0x7fffu + ((x.u >> 16) & 1u);   // RNE
  return (unsigned short)(r >> 16);
}

// pack two f32 -> bf16x2 dword (RNE), low half = a
__device__ __forceinline__ unsigned pack_rne(float a, float b) {
  unsigned ua = __float_as_uint(a), ub = __float_as_uint(b);
  ua = ua + 0x7fffu + ((ua >> 16) & 1u);
  ub = ub + 0x7fffu + ((ub >> 16) & 1u);
  return __builtin_amdgcn_perm(ub, ua, 0x07060302);
}

// 16x16x16 bf16 MFMA: B-operand layout == 16x16 C/D layout (k=qd*4+j <-> row=qd*4+rg)
__device__ __forceinline__ f32x4 mfma16(short4v a, short4v b, f32x4 c) {
#if __has_builtin(__builtin_amdgcn_mfma_f32_16x16x16bf16_1k)
  return __builtin_amdgcn_mfma_f32_16x16x16bf16_1k(a, b, c, 0, 0, 0);
#else
  f32x4 d;
  asm volatile("v_mfma_f32_16x16x16_bf16 %0, %1, %2, %3\n\ts_nop 7\n\ts_nop 7"
               : "=v"(d) : "v"(a), "v"(b), "v"(c));
  return d;
#endif
}

__device__ __forceinline__ float fast_exp2(float p) {
#if __has_builtin(__builtin_amdgcn_exp2f)
  return __builtin_amdgcn_exp2f(p);
#else
  return exp2f(p);
#endif
}

// async global->LDS, 16B per lane; LDS dest = wave-uniform base + lane*16
__device__ __forceinline__ void gll16(const void* g, void* l) {
  __builtin_amdgcn_global_load_lds((const __attribute__((address_space(1))) void*)g,
                                   (__attribute__((address_space(3))) void*)l, 16, 0, 0);
}

// ---------------- fused prep: convert q/k/v, transpose weights, init out ----------------
__global__ __launch_bounds__(256) void k_prep(
    const float* __restrict__ q, const float* __restrict__ k, const float* __restrict__ v,
    const float* __restrict__ Wq, const float* __restrict__ Wk,
    const float* __restrict__ Wv, const float* __restrict__ Wo,
    const float* __restrict__ bo,
    unsigned short* __restrict__ qb, unsigned short* __restrict__ kb,
    unsigned short* __restrict__ vb,
    unsigned short* __restrict__ Wqt, unsigned short* __restrict__ Wkt,
    unsigned short* __restrict__ Wvt, unsigned short* __restrict__ Wot,
    float* __restrict__ out) {
  __shared__ float tt[32][33];
  int b = blockIdx.x, tid = threadIdx.x;
  if (b < 12288) {                       // fp32->bf16 convert q/k/v
    int z = b >> 12;
    const float* src = z == 0 ? q : z == 1 ? k : v;
    unsigned short* dst = z == 0 ? qb : z == 1 ? kb : vb;
    size_t i = (size_t)(b & 4095) * 256 + tid;
    float4 f = ((const float4*)src)[i];
    ushort4 o;
    o.x = f2bf(f.x); o.y = f2bf(f.y); o.z = f2bf(f.z); o.w = f2bf(f.w);
    ((ushort4*)dst)[i] = o;
  } else if (b < 15424) {                // transpose+convert weights -> Wt[C][1024]
    int t = b - 12288;
    const float* W; unsigned short* Wt; int C, c0, r0;
    if (t < 3072) {
      int z = t >> 10;
      W = z == 0 ? Wq : z == 1 ? Wk : Wv;
      Wt = z == 0 ? Wqt : z == 1 ? Wkt : Wvt;
      C = 1024; int tile = t & 1023;
      c0 = (tile & 31) * 32; r0 = (tile >> 5) * 32;
    } else {
      int t2 = t - 3072;
      W = Wo; Wt = Wot; C = 64;
      c0 = (t2 & 1) * 32; r0 = (t2 >> 1) * 32;
    }
    int tx = tid & 31, ty = tid >> 5;
    #pragma unroll
    for (int i = 0; i < 32; i += 8)
      tt[ty + i][tx] = W[(size_t)(r0 + ty + i) * C + c0 + tx];
    __syncthreads();
    #pragma unroll
    for (int i = 0; i < 32; i += 8)
      Wt[(size_t)(c0 + ty + i) * 1024 + r0 + tx] = f2bf(tt[tx][ty + i]);
  } else {                               // out = broadcast bias (oproj atomics add onto it)
    int t3 = b - 15424;
    int i = t3 * 1024 + tid * 4;
    float4 bv4 = *(const float4*)(bo + (i & 63));
    *(float4*)(out + i) = bv4;
  }
}

// ---------------- QKV projection GEMM: [4096x1024]@[1024x1024]+b, BK=64 ----------------
__global__ __launch_bounds__(256, 3) void k_proj(
    const unsigned short* __restrict__ qb, const unsigned short* __restrict__ kb,
    const unsigned short* __restrict__ vb,
    const unsigned short* __restrict__ Wqt, const unsigned short* __restrict__ Wkt,
    const unsigned short* __restrict__ Wvt,
    const float* __restrict__ bq, const float* __restrict__ bk, const float* __restrict__ bv,
    unsigned short* __restrict__ qh, unsigned short* __restrict__ kh,
    unsigned short* __restrict__ vht) {
  int z = blockIdx.z;
  const unsigned short* A  = z == 0 ? qb  : z == 1 ? kb  : vb;
  const unsigned short* Bt = z == 0 ? Wqt : z == 1 ? Wkt : Wvt;
  const float* bias = z == 0 ? bq : z == 1 ? bk : bv;

  int m0 = blockIdx.y * 128;
  int n0 = blockIdx.x * 128;

  __shared__ __attribute__((aligned(16))) unsigned short As[128 * 64];
  __shared__ __attribute__((aligned(16))) unsigned short Bs[128 * 64];

  int tid = threadIdx.x;
  int w = tid >> 6, lane = tid & 63;
  int wm = w >> 1, wn = w & 1;
  int lr = lane & 15, lk = lane >> 4;

  f32x4 acc[4][4] = {};

  for (int k0 = 0; k0 < 1024; k0 += 64) {
    #pragma unroll
    for (int i = 0; i < 4; ++i) {        // A tile 128x64
      int cc = i * 256 + tid;
      int r = cc >> 3;
      int j = (cc & 7) ^ (r & 7);
      gll16(A + (size_t)(m0 + r) * 1024 + k0 + j * 8, As + (size_t)(i * 256 + w * 64) * 8);
    }
    #pragma unroll
    for (int i = 0; i < 4; ++i) {        // B tile 128x64
      int cc = i * 256 + tid;
      int r = cc >> 3;
      int j = (cc & 7) ^ (r & 7);
      gll16(Bt + (size_t)(n0 + r) * 1024 + k0 + j * 8, Bs + (size_t)(i * 256 + w * 64) * 8);
    }
    __syncthreads();
    #pragma unroll
    for (int ks = 0; ks < 2; ++ks) {
      bf16x8 af[4], bfr[4];
      #pragma unroll
      for (int mt = 0; mt < 4; ++mt) {
        int r = wm * 64 + mt * 16 + lr;
        af[mt] = *(const bf16x8*)(As + r * 64 + ((ks * 4 + lk) ^ (r & 7)) * 8);
      }
      #pragma unroll
      for (int nt = 0; nt < 4; ++nt) {
        int r = wn * 64 + nt * 16 + lr;
        bfr[nt] = *(const bf16x8*)(Bs + r * 64 + ((ks * 4 + lk) ^ (r & 7)) * 8);
      }
      #pragma unroll
      for (int mt = 0; mt < 4; ++mt)
        #pragma unroll
        for (int nt = 0; nt < 4; ++nt)
          acc[mt][nt] = __builtin_amdgcn_mfma_f32_16x16x32_bf16(af[mt], bfr[nt], acc[mt][nt], 0, 0, 0);
    }
    __syncthreads();
  }

  // epilogue: bias (+scale for q), scatter to attention layouts
  #pragma unroll
  for (int nt = 0; nt < 4; ++nt) {
    int n = n0 + wn * 64 + nt * 16 + lr;
    float bv_ = bias[n];
    int h = n >> 6, d = n & 63;
    #pragma unroll
    for (int mt = 0; mt < 4; ++mt) {
      int mbase = m0 + wm * 64 + mt * 16 + lk * 4;
      int b = mbase >> 11, s = mbase & 2047;
      if (z == 2) {
        size_t o = ((size_t)(b * 16 + h) * 64 + d) * 2048 + s;   // 4 consecutive s
        ushort4 pk;
        pk.x = f2bf(acc[mt][nt][0] + bv_);
        pk.y = f2bf(acc[mt][nt][1] + bv_);
        pk.z = f2bf(acc[mt][nt][2] + bv_);
        pk.w = f2bf(acc[mt][nt][3] + bv_);
        *(ushort4*)(vht + o) = pk;
      } else {
        unsigned short* dst = (z == 0) ? qh : kh;
        float sc = (z == 0) ? 0.125f : 1.0f;   // scale = ATT_DIM^-0.5, exact pow2
        #pragma unroll
        for (int rg = 0; rg < 4; ++rg) {
          float val = (acc[mt][nt][rg] + bv_) * sc;
          float pv = __shfl_xor(val, 1, 64);
          if ((lr & 1) == 0) {   // even-d lane packs (d, d+1) -> 4B store
            unsigned pkv = pack_rne(val, pv);
            *(unsigned*)(dst + ((size_t)(b * 16 + h) * 2048 + (s + rg)) * 64 + d) = pkv;
          }
        }
      }
    }
  }
}

// ---------------- fused attention, S^T formulation, 128q per block ----------------
// 4 waves: wm = key-half of 64-key tile, wn = 64q-half of the 128q block; each wave
// computes 32 keys x 64 q. Same K/V LDS tiles as before but amortized over 2x scores:
// per-CU LDS traffic halves per unit work. S^T = K @ Q^T -> P^T in C-layout, which IS
// the 16x16x16 B-operand layout, so PV consumes the packed weights from registers.
// Weight: w ∝ exp2(log2e*0.5*tanh(s/2)), odd poly in s (|s| clamped to 4), single
// v_exp; bf16 truncation via v_perm; denominator = ones-row MFMA over the SAME
// truncated bf16 P the numerator uses (per-row exponent offsets cancel in the ratio).
__global__ __launch_bounds__(256, 2) void k_attn(
    const unsigned short* __restrict__ qh, const unsigned short* __restrict__ kh,
    const unsigned short* __restrict__ vht, unsigned short* __restrict__ attout) {
  int bh = blockIdx.y;
  int q0 = blockIdx.x * 128;
  const unsigned short* Q = qh + (size_t)bh * 2048 * 64;
  const unsigned short* Kg = kh + (size_t)bh * 2048 * 64;
  const unsigned short* Vg = vht + (size_t)bh * 64 * 2048;   // [64 d][2048 s]

  __shared__ __attribute__((aligned(16))) unsigned short KV[17408];  // 2x(K 4096 + V 4096) + pad
  __shared__ float lsum[128];

  int tid = threadIdx.x;
  int w = tid >> 6, lane = tid & 63;
  int wm = w >> 1, wn = w & 1;          // wm: key-half of tile, wn: 64q-half
  int c = lane & 15, qd = lane >> 4;

  // Q fragments straight from global (one-time, 16B/lane): B[k=d][n=q]
  bf16x8 qf[4][2];
  #pragma unroll
  for (int nt = 0; nt < 4; ++nt)
    #pragma unroll
    for (int ks = 0; ks < 2; ++ks)
      qf[nt][ks] = *(const bf16x8*)(Q + (size_t)(q0 + wn * 64 + nt * 16 + c) * 64 + ks * 32 + qd * 8);

  // loop-invariant staging offsets (K rows stride 64; V rows stride 2048)
  size_t kOff[2], vOff[2]; int lOff[2];
  #pragma unroll
  for (int i = 0; i < 2; ++i) {
    int cc = i * 256 + w * 64 + lane;
    int r = cc >> 3;
    int j = (cc & 7) ^ (r & 7);
    kOff[i] = (size_t)r * 64 + j * 8;
    vOff[i] = (size_t)r * 2048 + j * 8;
    lOff[i] = (i * 256 + w * 64) * 8;
  }

  // stage tile 0 into buffer 0
  #pragma unroll
  for (int i = 0; i < 2; ++i) {
    gll16(Kg + kOff[i], KV + lOff[i]);
    gll16(Vg + vOff[i], KV + 4096 + lOff[i]);
  }
  Kg += 4096; Vg += 64;

  // loop-invariant frag addresses
  int kfA[2][2], vfA[4][2];
  #pragma unroll
  for (int mt = 0; mt < 2; ++mt) {
    int r = wm * 32 + mt * 16 + c;
    #pragma unroll
    for (int ks = 0; ks < 2; ++ks)
      kfA[mt][ks] = r * 64 + ((ks * 4 + qd) ^ (r & 7)) * 8;
  }
  #pragma unroll
  for (int dt = 0; dt < 4; ++dt) {
    int r = dt * 16 + c;
    #pragma unroll
    for (int mt = 0; mt < 2; ++mt)
      vfA[dt][mt] = r * 64 + ((4 * wm + 2 * mt + (qd >> 1)) ^ (r & 7)) * 8 + (qd & 1) * 4;
  }

  // ones A-fragment for denominator MFMA (bf16 1.0 = 0x3F80)
  const short one_bf = (short)0x3F80;
  short4v ones = {one_bf, one_bf, one_bf, one_bf};

  __syncthreads();

  f32x4 o[4][4] = {};                   // O^T partial [64 d][64 q] over this wave's keys
  f32x4 qacc[4] = {};                   // denominator: ones-row MFMA (all rows identical)

  for (int kt = 0; kt < 32; ++kt) {
    unsigned short* Kc = KV + (kt & 1) * 8192;
    unsigned short* Vc = Kc + 4096;
    if (kt + 1 < 32) {                  // prefetch next tile into other buffer
      unsigned short* Kn = KV + ((kt & 1) ^ 1) * 8192;
      #pragma unroll
      for (int i = 0; i < 2; ++i) {
        gll16(Kg + kOff[i], Kn + lOff[i]);
        gll16(Vg + vOff[i], Kn + 4096 + lOff[i]);
      }
      Kg += 4096; Vg += 64;
    }

    // S^T: D[key][q], wave tile 32 keys x 64 q
    f32x4 s[2][4] = {};
    #pragma unroll
    for (int ks = 0; ks < 2; ++ks) {
      bf16x8 kf[2];
      #pragma unroll
      for (int mt = 0; mt < 2; ++mt)
        kf[mt] = *(const bf16x8*)(Kc + kfA[mt][ks]);
      #pragma unroll
      for (int mt = 0; mt < 2; ++mt)
        #pragma unroll
        for (int nt = 0; nt < 4; ++nt)
          s[mt][nt] = __builtin_amdgcn_mfma_f32_16x16x32_bf16(kf[mt], qf[nt][ks], s[mt][nt], 0, 0, 0);
    }

    // w = exp2(poly(s)); truncate to bf16 via perm, pack into B-fragments
    unsigned pk[2][4][2];
    #pragma unroll
    for (int mt = 0; mt < 2; ++mt)
      #pragma unroll
      for (int nt = 0; nt < 4; ++nt) {
        unsigned wu[4];
        #pragma unroll
        for (int rg = 0; rg < 4; ++rg) {
          float sv = __builtin_amdgcn_fmed3f(s[mt][nt][rg], -4.0f, 4.0f);
          float z = sv * sv;
          // log2e * 0.5*tanh(s/2) interpolating odd poly, |s|<=4
          float p = fmaf(z, fmaf(z, fmaf(z, -3.9242863e-5f, 1.5674414e-3f),
                                  -2.6566200e-2f), 3.5838444e-1f) * sv;
          wu[rg] = __float_as_uint(fast_exp2(p));
        }
        pk[mt][nt][0] = __builtin_amdgcn_perm(wu[1], wu[0], 0x07060302);
        pk[mt][nt][1] = __builtin_amdgcn_perm(wu[3], wu[2], 0x07060302);
      }

    // PV: O^T[d][q] += V^T[d][k] P^T[k][q]; pk dwords ARE the 16x16x16 B-frags.
    short4v vfr[4][2];
    #pragma unroll
    for (int dt = 0; dt < 4; ++dt)
      #pragma unroll
      for (int mt = 0; mt < 2; ++mt)
        vfr[dt][mt] = *(const short4v*)(Vc + vfA[dt][mt]);
    #pragma unroll
    for (int nt = 0; nt < 4; ++nt)
      #pragma unroll
      for (int mt = 0; mt < 2; ++mt) {
        union { unsigned u[2]; short4v s4; } bb;
        bb.u[0] = pk[mt][nt][0];
        bb.u[1] = pk[mt][nt][1];
        qacc[nt] = mfma16(ones, bb.s4, qacc[nt]);
        #pragma unroll
        for (int dt = 0; dt < 4; ++dt)
          o[dt][nt] = mfma16(vfr[dt][mt], bb.s4, o[dt][nt]);
      }
    __syncthreads();
  }

  // cross-wave (wm) reduction through LDS (KV dead after last barrier).
  // Ored row stride 68 floats -> (c+qd) bank spread, 2-way only.
  float* Ored = (float*)KV;             // [128 q][stride 68] f32 <= 34816 B
  if (wm == 1) {
    #pragma unroll
    for (int nt = 0; nt < 4; ++nt) {
      int ql = wn * 64 + nt * 16 + c;
      #pragma unroll
      for (int dt = 0; dt < 4; ++dt)
        *(f32x4*)(Ored + ql * 68 + dt * 16 + qd * 4) = o[dt][nt];
      if (qd == 0) lsum[ql] = qacc[nt][0];
    }
  }
  __syncthreads();
  if (wm == 0) {
    int b = bh >> 4, h = bh & 15;
    #pragma unroll
    for (int nt = 0; nt < 4; ++nt) {
      int ql = wn * 64 + nt * 16 + c;
      float inv = __builtin_amdgcn_rcpf(qacc[nt][0] + lsum[ql]);
      size_t rowoff = ((size_t)(b * 2048 + q0 + ql)) * 1024 + h * 64;
      #pragma unroll
      for (int dt = 0; dt < 4; ++dt) {
        f32x4 r = *(const f32x4*)(Ored + ql * 68 + dt * 16 + qd * 4);
        f32x4 t = o[dt][nt];
        uint2 pko;
        pko.x = pack_rne((t[0] + r[0]) * inv, (t[1] + r[1]) * inv);
        pko.y = pack_rne((t[2] + r[2]) * inv, (t[3] + r[3]) * inv);
        *(uint2*)(attout + rowoff + dt * 16 + qd * 4) = pko;
      }
    }
  }
}

// ---------------- output projection: k-split x4, atomics onto bias-init out ----------------
__global__ __launch_bounds__(256) void k_oproj(
    const unsigned short* __restrict__ attout, const unsigned short* __restrict__ Wot,
    float* __restrict__ out) {
  int m0 = blockIdx.x * 64;
  int kbase = blockIdx.y * 256;
  __shared__ __attribute__((aligned(16))) unsigned short As[64 * 32];
  __shared__ __attribute__((aligned(16))) unsigned short Bs[64 * 32];
  int tid = threadIdx.x;
  int w = tid >> 6, lane = tid & 63;
  int lr = lane & 15, lk = lane >> 4;

  f32x4 acc[4] = {};

  for (int k0 = kbase; k0 < kbase + 256; k0 += 32) {
    {
      int cc = tid;
      int r = cc >> 2;
      int j = (cc & 3) ^ ((r >> 1) & 3);
      gll16(attout + (size_t)(m0 + r) * 1024 + k0 + j * 8, As + (size_t)(w * 64) * 8);
      gll16(Wot + (size_t)r * 1024 + k0 + j * 8, Bs + (size_t)(w * 64) * 8);
    }
    __syncthreads();
    bf16x8 af, bfr[4];
    {
      int r = w * 16 + lr;
      af = *(const bf16x8*)(As + r * 32 + ((lk ^ ((r >> 1) & 3))) * 8);
    }
    #pragma unroll
    for (int nt = 0; nt < 4; ++nt) {
      int r = nt * 16 + lr;
      bfr[nt] = *(const bf16x8*)(Bs + r * 32 + ((lk ^ ((r >> 1) & 3))) * 8);
    }
    #pragma unroll
    for (int nt = 0; nt < 4; ++nt)
      acc[nt] = __builtin_amdgcn_mfma_f32_16x16x32_bf16(af, bfr[nt], acc[nt], 0, 0, 0);
    __syncthreads();
  }
  #pragma unroll
  for (int nt = 0; nt < 4; ++nt) {
    int n = nt * 16 + lr;
    #pragma unroll
    for (int rg = 0; rg < 4; ++rg) {
      int m = m0 + w * 16 + lk * 4 + rg;
      atomicAdd(&out[(size_t)m * 64 + n], acc[nt][rg]);
    }
  }
}

extern "C" void kernel_launch(void* const* d_in, const int* in_sizes, int n_in,
                              void* d_out, int out_size, void* d_ws, size_t ws_size,
                              hipStream_t stream) {
  const float* q  = (const float*)d_in[0];
  const float* k  = (const float*)d_in[1];
  const float* v  = (const float*)d_in[2];
  const float* Wq = (const float*)d_in[3];
  const float* bq = (const float*)d_in[4];
  const float* Wk = (const float*)d_in[5];
  const float* bk = (const float*)d_in[6];
  const float* Wv = (const float*)d_in[7];
  const float* bv = (const float*)d_in[8];
  const float* Wo = (const float*)d_in[9];
  const float* bo = (const float*)d_in[10];
  float* out = (float*)d_out;

  char* ws = (char*)d_ws;
  const size_t MB = 1024 * 1024;
  unsigned short* qb  = (unsigned short*)(ws + 0 * MB);   // q bf16 [4096][1024]
  unsigned short* kb  = (unsigned short*)(ws + 8 * MB);
  unsigned short* vb  = (unsigned short*)(ws + 16 * MB);
  unsigned short* Wqt = (unsigned short*)(ws + 24 * MB);  // W^T bf16 [1024][1024]
  unsigned short* Wkt = (unsigned short*)(ws + 26 * MB);
  unsigned short* Wvt = (unsigned short*)(ws + 28 * MB);
  unsigned short* Wot = (unsigned short*)(ws + 30 * MB);  // Wo^T bf16 [64][1024]
  unsigned short* qh  = (unsigned short*)(ws + 32 * MB);  // [B,H,S,64] scaled
  unsigned short* kh  = (unsigned short*)(ws + 40 * MB);  // [B,H,S,64]
  unsigned short* vht = (unsigned short*)(ws + 48 * MB);  // [B,H,64,S]
  unsigned short* att = (unsigned short*)(ws + 56 * MB);  // [4096][1024]

  k_prep<<<dim3(15680), dim3(256), 0, stream>>>(q, k, v, Wq, Wk, Wv, Wo, bo,
                                                qb, kb, vb, Wqt, Wkt, Wvt, Wot, out);
  k_proj<<<dim3(8, 32, 3), dim3(256), 0, stream>>>(qb, kb, vb, Wqt, Wkt, Wvt,
                                                   bq, bk, bv, qh, kh, vht);
  k_attn<<<dim3(16, 32), dim3(256), 0, stream>>>(qh, kh, vht, att);
  k_oproj<<<dim3(64, 4), dim3(256), 0, stream>>>(att, Wot, out);
}